// Round 12
// baseline (466.643 us; speedup 1.0000x reference)
//
#include <hip/hip_runtime.h>
#include <hip/hip_bf16.h>
#include <math.h>
#include <stdint.h>

#define CC   256
#define HW   (128*128)       // 16384
#define MAT  (CC*CC)         // 65536
#define NBH  2048
#define N0   4096
#define N1   8192
#define N2   16384

typedef __attribute__((ext_vector_type(8))) short bf16x8;
typedef __attribute__((ext_vector_type(4))) float f32x4;

// ---------------------------------------------------------------------------
// k_mats1: A[i][c][d] = M_i[c][d] = sum_o Wf[i,o,c]*Wp[i,o,d]   (bf16 rows 0..255)
//          E[i][o][c2] = sum_c3 Wfuse[o, i*C+c3]*Wo[i,c3,c2]    (fp32 temp)
// ---------------------------------------------------------------------------
__global__ __launch_bounds__(256) void k_mats1(
    const float* __restrict__ Wp, const float* __restrict__ Wf,
    const float* __restrict__ Wo, const float* __restrict__ Wfu,
    __hip_bfloat16* __restrict__ A, float* __restrict__ E)
{
    int idx = blockIdx.x;
    int t = threadIdx.x;
    if (idx < 3*CC) {
        int i = idx >> 8, c = idx & 255;
        const float* wf = Wf + (size_t)i*MAT;
        const float* wp = Wp + (size_t)i*MAT;
        float acc = 0.f;
        for (int o = 0; o < CC; ++o)
            acc += wf[o*CC + c] * wp[o*CC + t];
        A[(size_t)i*512*CC + (size_t)c*CC + t] = __float2bfloat16(acc);
    } else {
        idx -= 3*CC;
        int i = idx >> 8, o = idx & 255;
        const float* wo = Wo + (size_t)i*MAT;
        const float* wfu = Wfu + (size_t)o*(3*CC) + i*CC;
        float acc = 0.f;
        for (int c3 = 0; c3 < CC; ++c3)
            acc += wfu[c3] * wo[c3*CC + t];
        E[(size_t)i*MAT + (size_t)o*CC + t] = acc;
    }
}

// ---------------------------------------------------------------------------
// k_mats2: A[i][256+o][d] = V_i[o][d] = sum_c E_i[o][c]*Wp[i,c,d]   (bf16)
// ---------------------------------------------------------------------------
__global__ __launch_bounds__(256) void k_mats2(
    const float* __restrict__ Wp, const float* __restrict__ E,
    __hip_bfloat16* __restrict__ A)
{
    int idx = blockIdx.x;
    int i = idx >> 8, o = idx & 255;
    int t = threadIdx.x;
    const float* e = E + (size_t)i*MAT + (size_t)o*CC;
    const float* wp = Wp + (size_t)i*MAT;
    float acc = 0.f;
    for (int c = 0; c < CC; ++c)
        acc += e[c] * wp[c*CC + t];
    A[(size_t)i*512*CC + (size_t)(256+o)*CC + t] = __float2bfloat16(acc);
}

// ---------------------------------------------------------------------------
// k_poolA: one (b,c) per block, 16-deep float4 staging. binsG[b][c][h][8].
// ---------------------------------------------------------------------------
__global__ __launch_bounds__(256, 4) void k_poolA(
    const float* __restrict__ x, float* __restrict__ binsG)
{
    int bc = blockIdx.x;                 // b*256 + c
    int t = threadIdx.x;
    const float4* xp = (const float4*)(x + (size_t)bc*HW) + t;
    __shared__ float bins[128][9];
    float4 v[16];
    #pragma unroll
    for (int i = 0; i < 16; ++i) v[i] = xp[i*256];
    int hb = t >> 5, bin = (t & 31) >> 2;
    #pragma unroll
    for (int i = 0; i < 16; ++i) {
        float s = v[i].x + v[i].y + v[i].z + v[i].w;
        s += __shfl_xor(s, 1);
        s += __shfl_xor(s, 2);           // sum of 16 w
        if ((t & 3) == 0) bins[i*8 + hb][bin] = s;
    }
    __syncthreads();
    int h = t >> 1, b0 = (t & 1) * 4;
    float4 o;
    o.x = bins[h][b0+0]; o.y = bins[h][b0+1];
    o.z = bins[h][b0+2]; o.w = bins[h][b0+3];
    ((float4*)binsG)[(size_t)bc*256 + t] = o;
}

// ---------------------------------------------------------------------------
// k_poolB: one bh per block, 256 thr (thread = c). binsG -> Bt (bf16).
// ---------------------------------------------------------------------------
__global__ __launch_bounds__(256) void k_poolB(
    const float* __restrict__ binsG, __hip_bfloat16* __restrict__ Bt)
{
    int bh = blockIdx.x;
    int b = bh >> 7, h = bh & 127;
    int c = threadIdx.x;
    const float* g = binsG + (((size_t)b*256 + c)*128 + h)*8;
    float4 lo = *(const float4*)(g);
    float4 hi = *(const float4*)(g + 4);
    float b8[8] = {lo.x, lo.y, lo.z, lo.w, hi.x, hi.y, hi.z, hi.w};

    __hip_bfloat16* B0 = Bt;
    __hip_bfloat16* B1 = Bt + (size_t)N0*CC;
    __hip_bfloat16* B2 = Bt + (size_t)(N0+N1)*CC;
    B0[((size_t)bh*2 + 0)*CC + c] = __float2bfloat16((b8[0]+b8[1]+b8[2]+b8[3]) * (1.f/64.f));
    B0[((size_t)bh*2 + 1)*CC + c] = __float2bfloat16((b8[4]+b8[5]+b8[6]+b8[7]) * (1.f/64.f));
    #pragma unroll
    for (int j = 0; j < 4; ++j)
        B1[((size_t)bh*4 + j)*CC + c] = __float2bfloat16((b8[2*j]+b8[2*j+1]) * (1.f/32.f));
    #pragma unroll
    for (int j = 0; j < 8; ++j)
        B2[((size_t)bh*8 + j)*CC + c] = __float2bfloat16(b8[j] * (1.f/16.f));
}

// ---------------------------------------------------------------------------
// k_gemm: 1792 blocks x 128 thr. Block tile 128x64, wave tile 64x64.
// Epilogue scatters BF16 into Cc[bh][512][16] (rows 0..255 mp, 256..511 vp).
// ---------------------------------------------------------------------------
__global__ __launch_bounds__(128) void k_gemm(
    const __hip_bfloat16* __restrict__ A,
    const __hip_bfloat16* __restrict__ Bt,
    __hip_bfloat16* __restrict__ Cc)
{
    int blk = blockIdx.x;
    int br, lb, LP, poff;
    if (blk < 256)      { br = 0; lb = blk;       LP = 1; poff = 0; }
    else if (blk < 768) { br = 1; lb = blk - 256; LP = 2; poff = 2; }
    else                { br = 2; lb = blk - 768; LP = 3; poff = 6; }
    size_t aoff  = (size_t)br*512*CC;
    size_t btoff = (br == 0) ? 0 : (br == 1 ? (size_t)N0*CC : (size_t)(N0+N1)*CC);
    const __hip_bfloat16* Ab = A  + aoff;
    const __hip_bfloat16* Bb = Bt + btoff;

    int rb = lb & 3, cb = lb >> 2;
    int wv = threadIdx.x >> 6, lane = threadIdx.x & 63;
    int row0 = rb*128 + wv*64;
    int col0 = cb*64;
    int lr = lane & 15, lk = (lane >> 4) * 8;

    f32x4 acc[4][4] = {};
    for (int kk = 0; kk < CC; kk += 32) {
        bf16x8 af[4], bfr[4];
        #pragma unroll
        for (int m = 0; m < 4; ++m)
            af[m] = *reinterpret_cast<const bf16x8*>(Ab + (size_t)(row0 + m*16 + lr)*CC + kk + lk);
        #pragma unroll
        for (int n = 0; n < 4; ++n)
            bfr[n] = *reinterpret_cast<const bf16x8*>(Bb + (size_t)(col0 + n*16 + lr)*CC + kk + lk);
        #pragma unroll
        for (int m = 0; m < 4; ++m)
            #pragma unroll
            for (int n = 0; n < 4; ++n)
                acc[m][n] = __builtin_amdgcn_mfma_f32_16x16x32_bf16(af[m], bfr[n], acc[m][n], 0, 0, 0);
    }

    int cr = (lane >> 4) * 4, ccol = lane & 15;
    int pm = (1 << LP) - 1;
    #pragma unroll
    for (int m = 0; m < 4; ++m) {
        #pragma unroll
        for (int n = 0; n < 4; ++n) {
            int colg = col0 + n*16 + ccol;
            int bh = colg >> LP, p = colg & pm;
            __hip_bfloat16* dst = Cc + (size_t)bh*8192 + poff + p;
            #pragma unroll
            for (int j = 0; j < 4; ++j) {
                int r = row0 + m*16 + cr + j;
                dst[r*16] = __float2bfloat16(acc[m][n][j]);
            }
        }
    }
}

// ---------------------------------------------------------------------------
// k_main v12: block = bh, 4 waves = c mod 4, lane owns w-pair (float2).
// 8 batches x 8 channels (FIX: v11 only covered 128 channels with 4 batches).
// Deep MLP via double-buffered 8-deep VGPR load batches + sched_barrier(0):
// load A; load B; SB; {consume A; load A'}; SB; ... 16 float2 loads live.
// Weights: bf16 Cc rows via wave-uniform s_loads, shift/mask unpack.
// ---------------------------------------------------------------------------
template<int L>
__device__ __forceinline__ void softmax2(float2* a) {
    float mx = a[0].x, my = a[0].y;
    #pragma unroll
    for (int j = 1; j < L; ++j) { mx = fmaxf(mx, a[j].x); my = fmaxf(my, a[j].y); }
    float sx = 0.f, sy = 0.f;
    #pragma unroll
    for (int j = 0; j < L; ++j) {
        a[j].x = __expf(a[j].x - mx); sx += a[j].x;
        a[j].y = __expf(a[j].y - my); sy += a[j].y;
    }
    float rx = 1.f / sx, ry = 1.f / sy;
    #pragma unroll
    for (int j = 0; j < L; ++j) { a[j].x *= rx; a[j].y *= ry; }
}

__global__ __launch_bounds__(256, 4) void k_main(
    const float* __restrict__ x, const __hip_bfloat16* __restrict__ Cc,
    float* __restrict__ out)
{
    int bh = blockIdx.x;
    int b = bh >> 7, h = bh & 127;
    int t = threadIdx.x;
    int lane = t & 63;
    int wv = __builtin_amdgcn_readfirstlane(t >> 6);   // 0..3, wave-uniform
    const uint32_t* Cb = (const uint32_t*)(Cc + (size_t)bh*8192); // 8 dw / row
    const float2* x2 = (const float2*)x + ((size_t)b*CC)*(HW/2) + h*64 + lane;
    float2*       o2 = (float2*)out     + ((size_t)b*CC)*(HW/2) + h*64 + lane;
    __shared__ float att_sx[2][64][15];                // 7680 B
    __shared__ float att_sy[2][64][15];                // 7680 B

    float2 att[14];
    #pragma unroll
    for (int p = 0; p < 14; ++p) att[p] = make_float2(0.f, 0.f);

    float2 xa[8], xb[8];

    // channel of (batch cc in 0..7, slot j in 0..7) for this wave:
    // covers (cc*8+j) in 0..63, *4 + wv -> all 256 channels.
    #define CH(cc, j) (((cc)*8 + (j))*4 + wv)

    #define LOADB(buf, cc)                                                  \
        _Pragma("unroll")                                                   \
        for (int j = 0; j < 8; ++j)                                         \
            buf[j] = x2[(size_t)CH(cc, j) * (HW/2)];

    #define CONS_A(buf, cc)                                                 \
        _Pragma("unroll")                                                   \
        for (int j = 0; j < 8; ++j) {                                       \
            int c = CH(cc, j);                                              \
            const uint32_t* wr = Cb + (size_t)c*8;                          \
            float2 xv = buf[j];                                             \
            _Pragma("unroll")                                               \
            for (int p = 0; p < 7; ++p) {                                   \
                uint32_t u = wr[p];                                         \
                float mlo = __uint_as_float(u << 16);                       \
                float mhi = __uint_as_float(u & 0xFFFF0000u);               \
                att[2*p].x   += xv.x * mlo;  att[2*p].y   += xv.y * mlo;    \
                att[2*p+1].x += xv.x * mhi;  att[2*p+1].y += xv.y * mhi;    \
            }                                                               \
        }

    #define CONS_B(buf, cc)                                                 \
        _Pragma("unroll")                                                   \
        for (int j = 0; j < 8; ++j) {                                       \
            int c = CH(cc, j);                                              \
            const uint32_t* wr = Cb + (size_t)(256 + c)*8;                  \
            float2 acc = buf[j];                                            \
            _Pragma("unroll")                                               \
            for (int p = 0; p < 7; ++p) {                                   \
                uint32_t u = wr[p];                                         \
                float vlo = __uint_as_float(u << 16);                       \
                float vhi = __uint_as_float(u & 0xFFFF0000u);               \
                acc.x += att[2*p].x * vlo;   acc.y += att[2*p].y * vlo;     \
                acc.x += att[2*p+1].x * vhi; acc.y += att[2*p+1].y * vhi;   \
            }                                                               \
            o2[(size_t)c * (HW/2)] = acc;                                   \
        }

    #define SB __builtin_amdgcn_sched_barrier(0)

    // ---- pass A: att logits, 8 batches, double-buffered ----
    LOADB(xa, 0); LOADB(xb, 1); SB;
    CONS_A(xa, 0); LOADB(xa, 2); SB;
    CONS_A(xb, 1); LOADB(xb, 3); SB;
    CONS_A(xa, 2); LOADB(xa, 4); SB;
    CONS_A(xb, 3); LOADB(xb, 5); SB;
    CONS_A(xa, 4); LOADB(xa, 6); SB;
    CONS_A(xb, 5); LOADB(xb, 7); SB;
    CONS_A(xa, 6); SB;
    CONS_A(xb, 7);

    // ---- cross-wave att reduce + softmax ----
    if (wv >= 2) {
        #pragma unroll
        for (int p = 0; p < 14; ++p) {
            att_sx[wv-2][lane][p] = att[p].x;
            att_sy[wv-2][lane][p] = att[p].y;
        }
    }
    __syncthreads();
    if (wv < 2) {
        #pragma unroll
        for (int p = 0; p < 14; ++p) {
            att[p].x += att_sx[wv][lane][p];
            att[p].y += att_sy[wv][lane][p];
        }
        if (wv == 1) {
            #pragma unroll
            for (int p = 0; p < 14; ++p) {
                att_sx[1][lane][p] = att[p].x;
                att_sy[1][lane][p] = att[p].y;
            }
        }
    }
    __syncthreads();
    if (wv == 0) {
        #pragma unroll
        for (int p = 0; p < 14; ++p) {
            att[p].x = (att[p].x + att_sx[1][lane][p]) * 0.0625f;
            att[p].y = (att[p].y + att_sy[1][lane][p]) * 0.0625f;
        }
        softmax2<2>(att + 0);
        softmax2<4>(att + 2);
        softmax2<8>(att + 6);
        #pragma unroll
        for (int p = 0; p < 14; ++p) {
            att_sx[0][lane][p] = att[p].x;
            att_sy[0][lane][p] = att[p].y;
        }
    }
    __syncthreads();
    #pragma unroll
    for (int p = 0; p < 14; ++p) {
        att[p].x = att_sx[0][lane][p];
        att[p].y = att_sy[0][lane][p];
    }

    // ---- pass B: out = x + att.vp, same deep-MLP structure ----
    LOADB(xa, 0); LOADB(xb, 1); SB;
    CONS_B(xa, 0); LOADB(xa, 2); SB;
    CONS_B(xb, 1); LOADB(xb, 3); SB;
    CONS_B(xa, 2); LOADB(xa, 4); SB;
    CONS_B(xb, 3); LOADB(xb, 5); SB;
    CONS_B(xa, 4); LOADB(xa, 6); SB;
    CONS_B(xb, 5); LOADB(xb, 7); SB;
    CONS_B(xa, 6); SB;
    CONS_B(xb, 7);

    #undef CH
    #undef LOADB
    #undef CONS_A
    #undef CONS_B
    #undef SB
}

// ---------------------------------------------------------------------------
extern "C" void kernel_launch(void* const* d_in, const int* in_sizes, int n_in,
                              void* d_out, int out_size, void* d_ws, size_t ws_size,
                              hipStream_t stream)
{
    (void)in_sizes; (void)n_in; (void)out_size; (void)ws_size;
    const float* x   = (const float*)d_in[0];
    const float* Wp  = (const float*)d_in[1];
    const float* Wf  = (const float*)d_in[2];
    const float* Wo  = (const float*)d_in[3];
    const float* Wfu = (const float*)d_in[4];
    float* out = (float*)d_out;

    // workspace layout (bytes):
    //   E     fp32 3*MAT          @ 0         =   786432
    //   A     bf16 3*512*256      @ 786432    =   786432
    //   Bt    bf16 28672*256      @ 1572864   = 14680064
    //   Cc    bf16 2048*512*16    @ 16252928  = 33554432
    //   (binsG fp32 16.8 MB aliases Cc: consumed by poolB before k_gemm)
    char* wsb = (char*)d_ws;
    float*          E     = (float*)wsb;
    __hip_bfloat16* A     = (__hip_bfloat16*)(wsb + 786432);
    __hip_bfloat16* Bt    = (__hip_bfloat16*)(wsb + 1572864);
    __hip_bfloat16* Cc    = (__hip_bfloat16*)(wsb + 16252928);
    float*          binsG = (float*)(wsb + 16252928);

    k_mats1<<<dim3(6*CC),  dim3(256), 0, stream>>>(Wp, Wf, Wo, Wfu, A, E);
    k_mats2<<<dim3(3*CC),  dim3(256), 0, stream>>>(Wp, E, A);
    k_poolA<<<dim3(4096),  dim3(256), 0, stream>>>(x, binsG);
    k_poolB<<<dim3(NBH),   dim3(256), 0, stream>>>(binsG, Bt);
    k_gemm <<<dim3(1792),  dim3(128), 0, stream>>>(A, Bt, Cc);
    k_main <<<dim3(NBH),   dim3(256), 0, stream>>>(x, Cc, out);
}

// Round 13
// 390.731 us; speedup vs baseline: 1.1943x; 1.1943x over previous
//
#include <hip/hip_runtime.h>
#include <hip/hip_bf16.h>
#include <math.h>
#include <stdint.h>

#define CC   256
#define HW   (128*128)       // 16384
#define MAT  (CC*CC)         // 65536
#define NBH  2048
#define N0   4096
#define N1   8192
#define N2   16384

typedef __attribute__((ext_vector_type(8))) short bf16x8;
typedef __attribute__((ext_vector_type(4))) float f32x4;
typedef __attribute__((address_space(3))) uint32_t lds_u32_t;
typedef __attribute__((address_space(1))) const uint32_t glb_u32_t;

// ---------------------------------------------------------------------------
// k_mats1: A[i][c][d] = M_i[c][d] = sum_o Wf[i,o,c]*Wp[i,o,d]   (bf16 rows 0..255)
//          E[i][o][c2] = sum_c3 Wfuse[o, i*C+c3]*Wo[i,c3,c2]    (fp32 temp)
// ---------------------------------------------------------------------------
__global__ __launch_bounds__(256) void k_mats1(
    const float* __restrict__ Wp, const float* __restrict__ Wf,
    const float* __restrict__ Wo, const float* __restrict__ Wfu,
    __hip_bfloat16* __restrict__ A, float* __restrict__ E)
{
    int idx = blockIdx.x;
    int t = threadIdx.x;
    if (idx < 3*CC) {
        int i = idx >> 8, c = idx & 255;
        const float* wf = Wf + (size_t)i*MAT;
        const float* wp = Wp + (size_t)i*MAT;
        float acc = 0.f;
        for (int o = 0; o < CC; ++o)
            acc += wf[o*CC + c] * wp[o*CC + t];
        A[(size_t)i*512*CC + (size_t)c*CC + t] = __float2bfloat16(acc);
    } else {
        idx -= 3*CC;
        int i = idx >> 8, o = idx & 255;
        const float* wo = Wo + (size_t)i*MAT;
        const float* wfu = Wfu + (size_t)o*(3*CC) + i*CC;
        float acc = 0.f;
        for (int c3 = 0; c3 < CC; ++c3)
            acc += wfu[c3] * wo[c3*CC + t];
        E[(size_t)i*MAT + (size_t)o*CC + t] = acc;
    }
}

// ---------------------------------------------------------------------------
// k_mats2: A[i][256+o][d] = V_i[o][d] = sum_c E_i[o][c]*Wp[i,c,d]   (bf16)
// ---------------------------------------------------------------------------
__global__ __launch_bounds__(256) void k_mats2(
    const float* __restrict__ Wp, const float* __restrict__ E,
    __hip_bfloat16* __restrict__ A)
{
    int idx = blockIdx.x;
    int i = idx >> 8, o = idx & 255;
    int t = threadIdx.x;
    const float* e = E + (size_t)i*MAT + (size_t)o*CC;
    const float* wp = Wp + (size_t)i*MAT;
    float acc = 0.f;
    for (int c = 0; c < CC; ++c)
        acc += e[c] * wp[c*CC + t];
    A[(size_t)i*512*CC + (size_t)(256+o)*CC + t] = __float2bfloat16(acc);
}

// ---------------------------------------------------------------------------
// k_poolA: one (b,c) per block, 16-deep float4 staging. binsG[b][c][h][8].
// ---------------------------------------------------------------------------
__global__ __launch_bounds__(256, 4) void k_poolA(
    const float* __restrict__ x, float* __restrict__ binsG)
{
    int bc = blockIdx.x;                 // b*256 + c
    int t = threadIdx.x;
    const float4* xp = (const float4*)(x + (size_t)bc*HW) + t;
    __shared__ float bins[128][9];
    float4 v[16];
    #pragma unroll
    for (int i = 0; i < 16; ++i) v[i] = xp[i*256];
    int hb = t >> 5, bin = (t & 31) >> 2;
    #pragma unroll
    for (int i = 0; i < 16; ++i) {
        float s = v[i].x + v[i].y + v[i].z + v[i].w;
        s += __shfl_xor(s, 1);
        s += __shfl_xor(s, 2);           // sum of 16 w
        if ((t & 3) == 0) bins[i*8 + hb][bin] = s;
    }
    __syncthreads();
    int h = t >> 1, b0 = (t & 1) * 4;
    float4 o;
    o.x = bins[h][b0+0]; o.y = bins[h][b0+1];
    o.z = bins[h][b0+2]; o.w = bins[h][b0+3];
    ((float4*)binsG)[(size_t)bc*256 + t] = o;
}

// ---------------------------------------------------------------------------
// k_poolB: one bh per block, 256 thr (thread = c). binsG -> Bt (bf16).
// ---------------------------------------------------------------------------
__global__ __launch_bounds__(256) void k_poolB(
    const float* __restrict__ binsG, __hip_bfloat16* __restrict__ Bt)
{
    int bh = blockIdx.x;
    int b = bh >> 7, h = bh & 127;
    int c = threadIdx.x;
    const float* g = binsG + (((size_t)b*256 + c)*128 + h)*8;
    float4 lo = *(const float4*)(g);
    float4 hi = *(const float4*)(g + 4);
    float b8[8] = {lo.x, lo.y, lo.z, lo.w, hi.x, hi.y, hi.z, hi.w};

    __hip_bfloat16* B0 = Bt;
    __hip_bfloat16* B1 = Bt + (size_t)N0*CC;
    __hip_bfloat16* B2 = Bt + (size_t)(N0+N1)*CC;
    B0[((size_t)bh*2 + 0)*CC + c] = __float2bfloat16((b8[0]+b8[1]+b8[2]+b8[3]) * (1.f/64.f));
    B0[((size_t)bh*2 + 1)*CC + c] = __float2bfloat16((b8[4]+b8[5]+b8[6]+b8[7]) * (1.f/64.f));
    #pragma unroll
    for (int j = 0; j < 4; ++j)
        B1[((size_t)bh*4 + j)*CC + c] = __float2bfloat16((b8[2*j]+b8[2*j+1]) * (1.f/32.f));
    #pragma unroll
    for (int j = 0; j < 8; ++j)
        B2[((size_t)bh*8 + j)*CC + c] = __float2bfloat16(b8[j] * (1.f/16.f));
}

// ---------------------------------------------------------------------------
// k_gemm: 1792 blocks x 128 thr. Block tile 128x64, wave tile 64x64.
// Epilogue scatters BF16 into Cc[bh][512][16] (rows 0..255 mp, 256..511 vp).
// ---------------------------------------------------------------------------
__global__ __launch_bounds__(128) void k_gemm(
    const __hip_bfloat16* __restrict__ A,
    const __hip_bfloat16* __restrict__ Bt,
    __hip_bfloat16* __restrict__ Cc)
{
    int blk = blockIdx.x;
    int br, lb, LP, poff;
    if (blk < 256)      { br = 0; lb = blk;       LP = 1; poff = 0; }
    else if (blk < 768) { br = 1; lb = blk - 256; LP = 2; poff = 2; }
    else                { br = 2; lb = blk - 768; LP = 3; poff = 6; }
    size_t aoff  = (size_t)br*512*CC;
    size_t btoff = (br == 0) ? 0 : (br == 1 ? (size_t)N0*CC : (size_t)(N0+N1)*CC);
    const __hip_bfloat16* Ab = A  + aoff;
    const __hip_bfloat16* Bb = Bt + btoff;

    int rb = lb & 3, cb = lb >> 2;
    int wv = threadIdx.x >> 6, lane = threadIdx.x & 63;
    int row0 = rb*128 + wv*64;
    int col0 = cb*64;
    int lr = lane & 15, lk = (lane >> 4) * 8;

    f32x4 acc[4][4] = {};
    for (int kk = 0; kk < CC; kk += 32) {
        bf16x8 af[4], bfr[4];
        #pragma unroll
        for (int m = 0; m < 4; ++m)
            af[m] = *reinterpret_cast<const bf16x8*>(Ab + (size_t)(row0 + m*16 + lr)*CC + kk + lk);
        #pragma unroll
        for (int n = 0; n < 4; ++n)
            bfr[n] = *reinterpret_cast<const bf16x8*>(Bb + (size_t)(col0 + n*16 + lr)*CC + kk + lk);
        #pragma unroll
        for (int m = 0; m < 4; ++m)
            #pragma unroll
            for (int n = 0; n < 4; ++n)
                acc[m][n] = __builtin_amdgcn_mfma_f32_16x16x32_bf16(af[m], bfr[n], acc[m][n], 0, 0, 0);
    }

    int cr = (lane >> 4) * 4, ccol = lane & 15;
    int pm = (1 << LP) - 1;
    #pragma unroll
    for (int m = 0; m < 4; ++m) {
        #pragma unroll
        for (int n = 0; n < 4; ++n) {
            int colg = col0 + n*16 + ccol;
            int bh = colg >> LP, p = colg & pm;
            __hip_bfloat16* dst = Cc + (size_t)bh*8192 + poff + p;
            #pragma unroll
            for (int j = 0; j < 4; ++j) {
                int r = row0 + m*16 + cr + j;
                dst[r*16] = __float2bfloat16(acc[m][n][j]);
            }
        }
    }
}

// ---------------------------------------------------------------------------
// k_main v13: one bh per block, 512 thr = 8 waves. ALL of x[b][:][h][:] made
// LDS-resident (128 KB): each wave owns 32 channels, issues its 16 x 1KB DMAs
// UPFRONT, consumes pass-A logits with laddered vmcnt(15-j) (pure-read phase,
// no barriers). 4-barrier cross-wave reduce + softmax. Pass B: ZERO global
// loads (residual from LDS), pure FMA + store stream (pure-write phase).
// ---------------------------------------------------------------------------
template<int L>
__device__ __forceinline__ void softmax2(float2* a) {
    float mx = a[0].x, my = a[0].y;
    #pragma unroll
    for (int j = 1; j < L; ++j) { mx = fmaxf(mx, a[j].x); my = fmaxf(my, a[j].y); }
    float sx = 0.f, sy = 0.f;
    #pragma unroll
    for (int j = 0; j < L; ++j) {
        a[j].x = __expf(a[j].x - mx); sx += a[j].x;
        a[j].y = __expf(a[j].y - my); sy += a[j].y;
    }
    float rx = 1.f / sx, ry = 1.f / sy;
    #pragma unroll
    for (int j = 0; j < L; ++j) { a[j].x *= rx; a[j].y *= ry; }
}

__global__ __launch_bounds__(512, 1) void k_main(
    const float* __restrict__ x, const __hip_bfloat16* __restrict__ Cc,
    float* __restrict__ out)
{
    int bh = blockIdx.x;
    int b = bh >> 7, h = bh & 127;
    int t = threadIdx.x;
    int lane = t & 63;
    int wv = __builtin_amdgcn_readfirstlane(t >> 6);   // 0..7, wave-uniform
    const uint32_t* Cb = (const uint32_t*)(Cc + (size_t)bh*8192); // 8 dw / row
    const float* xg = x + ((size_t)b*CC)*HW + h*128;
    float2* o2 = (float2*)out + ((size_t)b*CC)*(HW/2) + h*64 + lane;

    __shared__ float  xlds[256][128];                  // 131072 B
    __shared__ float2 red[4][64][15];                  // 30720 B  (total 158 KB)

    float2 att[14];
    #pragma unroll
    for (int p = 0; p < 14; ++p) att[p] = make_float2(0.f, 0.f);

    // per-lane DMA global source: lanes 0..31 -> channel c0, 32..63 -> c0+1
    const float* gsrc = xg + (size_t)(lane >> 5)*HW + (lane & 31)*4;

    // ---- issue ALL 16 DMAs (this wave's 32 channels, 1 KB each) ----
    #pragma unroll
    for (int j = 0; j < 16; ++j) {
        int c0 = wv*32 + 2*j;
        __builtin_amdgcn_global_load_lds(
            (glb_u32_t*)(gsrc + (size_t)c0*HW),
            (lds_u32_t*)&xlds[c0][0], 16, 0, 0);
    }
    __builtin_amdgcn_sched_barrier(0);

    // ---- pass A: consume pair j after its DMA lands (vmcnt ladder) ----
    #define CONSA(J, VM)                                                    \
        asm volatile("s_waitcnt vmcnt(" #VM ")" ::: "memory");              \
        __builtin_amdgcn_sched_barrier(0);                                  \
        {                                                                   \
            const int c0 = wv*32 + 2*(J);                                   \
            const uint32_t* wr0 = Cb + (size_t)c0*8;                        \
            float2 x0 = *(const float2*)&xlds[c0][lane*2];                  \
            float2 x1 = *(const float2*)&xlds[c0+1][lane*2];                \
            _Pragma("unroll")                                               \
            for (int p = 0; p < 7; ++p) {                                   \
                uint32_t u0 = wr0[p], u1 = wr0[8+p];                        \
                float a0 = __uint_as_float(u0 << 16);                       \
                float b0 = __uint_as_float(u0 & 0xFFFF0000u);               \
                float a1 = __uint_as_float(u1 << 16);                       \
                float b1 = __uint_as_float(u1 & 0xFFFF0000u);               \
                att[2*p].x   += x0.x*a0 + x1.x*a1;                          \
                att[2*p].y   += x0.y*a0 + x1.y*a1;                          \
                att[2*p+1].x += x0.x*b0 + x1.x*b1;                          \
                att[2*p+1].y += x0.y*b0 + x1.y*b1;                          \
            }                                                               \
        }

    CONSA(0, 15); CONSA(1, 14); CONSA(2, 13); CONSA(3, 12);
    CONSA(4, 11); CONSA(5, 10); CONSA(6,  9); CONSA(7,  8);
    CONSA(8,  7); CONSA(9,  6); CONSA(10, 5); CONSA(11, 4);
    CONSA(12, 3); CONSA(13, 2); CONSA(14, 1); CONSA(15, 0);
    #undef CONSA

    // ---- cross-wave reduce (8 partials) + softmax ----
    if (wv >= 4) {
        #pragma unroll
        for (int p = 0; p < 14; ++p) red[wv-4][lane][p] = att[p];
    }
    __syncthreads();
    if (wv < 4) {
        #pragma unroll
        for (int p = 0; p < 14; ++p) {
            float2 r = red[wv][lane][p];
            att[p].x += r.x; att[p].y += r.y;
        }
    }
    __syncthreads();
    if (wv >= 1 && wv < 4) {
        #pragma unroll
        for (int p = 0; p < 14; ++p) red[wv][lane][p] = att[p];
    }
    __syncthreads();
    if (wv == 0) {
        #pragma unroll
        for (int p = 0; p < 14; ++p) {
            float2 r1 = red[1][lane][p], r2 = red[2][lane][p], r3 = red[3][lane][p];
            att[p].x = (att[p].x + r1.x + r2.x + r3.x) * 0.0625f;
            att[p].y = (att[p].y + r1.y + r2.y + r3.y) * 0.0625f;
        }
        softmax2<2>(att + 0);
        softmax2<4>(att + 2);
        softmax2<8>(att + 6);
        #pragma unroll
        for (int p = 0; p < 14; ++p) red[0][lane][p] = att[p];
    }
    __syncthreads();
    #pragma unroll
    for (int p = 0; p < 14; ++p) att[p] = red[0][lane][p];

    // ---- pass B: zero global loads; residual from LDS; pure store stream ----
    #pragma unroll 8
    for (int jj = 0; jj < 32; ++jj) {
        int ch = wv*32 + jj;
        const uint32_t* wr = Cb + (size_t)(256 + ch)*8;
        float2 xv = *(const float2*)&xlds[ch][lane*2];
        float2 acc = xv;
        #pragma unroll
        for (int p = 0; p < 7; ++p) {
            uint32_t u = wr[p];
            float vlo = __uint_as_float(u << 16);
            float vhi = __uint_as_float(u & 0xFFFF0000u);
            acc.x += att[2*p].x * vlo + att[2*p+1].x * vhi;
            acc.y += att[2*p].y * vlo + att[2*p+1].y * vhi;
        }
        o2[(size_t)ch * (HW/2)] = acc;
    }
}

// ---------------------------------------------------------------------------
extern "C" void kernel_launch(void* const* d_in, const int* in_sizes, int n_in,
                              void* d_out, int out_size, void* d_ws, size_t ws_size,
                              hipStream_t stream)
{
    (void)in_sizes; (void)n_in; (void)out_size; (void)ws_size;
    const float* x   = (const float*)d_in[0];
    const float* Wp  = (const float*)d_in[1];
    const float* Wf  = (const float*)d_in[2];
    const float* Wo  = (const float*)d_in[3];
    const float* Wfu = (const float*)d_in[4];
    float* out = (float*)d_out;

    // workspace layout (bytes):
    //   E     fp32 3*MAT          @ 0         =   786432
    //   A     bf16 3*512*256      @ 786432    =   786432
    //   Bt    bf16 28672*256      @ 1572864   = 14680064
    //   Cc    bf16 2048*512*16    @ 16252928  = 33554432
    //   (binsG fp32 16.8 MB aliases Cc: consumed by poolB before k_gemm)
    char* wsb = (char*)d_ws;
    float*          E     = (float*)wsb;
    __hip_bfloat16* A     = (__hip_bfloat16*)(wsb + 786432);
    __hip_bfloat16* Bt    = (__hip_bfloat16*)(wsb + 1572864);
    __hip_bfloat16* Cc    = (__hip_bfloat16*)(wsb + 16252928);
    float*          binsG = (float*)(wsb + 16252928);

    k_mats1<<<dim3(6*CC),  dim3(256), 0, stream>>>(Wp, Wf, Wo, Wfu, A, E);
    k_mats2<<<dim3(3*CC),  dim3(256), 0, stream>>>(Wp, E, A);
    k_poolA<<<dim3(4096),  dim3(256), 0, stream>>>(x, binsG);
    k_poolB<<<dim3(NBH),   dim3(256), 0, stream>>>(binsG, Bt);
    k_gemm <<<dim3(1792),  dim3(128), 0, stream>>>(A, Bt, Cc);
    k_main <<<dim3(NBH),   dim3(512), 0, stream>>>(x, Cc, out);
}

// Round 14
// 341.233 us; speedup vs baseline: 1.3675x; 1.1451x over previous
//
#include <hip/hip_runtime.h>
#include <hip/hip_bf16.h>
#include <math.h>
#include <stdint.h>

#define CC   256
#define HW   (128*128)       // 16384
#define MAT  (CC*CC)         // 65536
#define NBH  2048
#define N0   4096
#define N1   8192
#define N2   16384

typedef __attribute__((ext_vector_type(8))) short bf16x8;
typedef __attribute__((ext_vector_type(4))) float f32x4;
typedef __attribute__((address_space(3))) uint32_t lds_u32_t;
typedef __attribute__((address_space(1))) const uint32_t glb_u32_t;

// ---------------------------------------------------------------------------
// k_cast: x fp32 -> xbf bf16, pure grid-stride stream (m13 copy pattern).
// ---------------------------------------------------------------------------
__global__ __launch_bounds__(256) void k_cast(
    const float4* __restrict__ x4, ushort4* __restrict__ xb4)
{
    int idx = blockIdx.x * 256 + threadIdx.x;
    int stride = gridDim.x * 256;
    #pragma unroll 4
    for (int i = idx; i < 16777216; i += stride) {     // 16*256*16384/4
        float4 v = x4[i];
        union { __hip_bfloat16 h[4]; ushort4 u; } c;
        c.h[0] = __float2bfloat16(v.x);
        c.h[1] = __float2bfloat16(v.y);
        c.h[2] = __float2bfloat16(v.z);
        c.h[3] = __float2bfloat16(v.w);
        xb4[i] = c.u;
    }
}

// ---------------------------------------------------------------------------
// k_mats1 / k_mats2: tiny weight-product kernels (unchanged).
// ---------------------------------------------------------------------------
__global__ __launch_bounds__(256) void k_mats1(
    const float* __restrict__ Wp, const float* __restrict__ Wf,
    const float* __restrict__ Wo, const float* __restrict__ Wfu,
    __hip_bfloat16* __restrict__ A, float* __restrict__ E)
{
    int idx = blockIdx.x;
    int t = threadIdx.x;
    if (idx < 3*CC) {
        int i = idx >> 8, c = idx & 255;
        const float* wf = Wf + (size_t)i*MAT;
        const float* wp = Wp + (size_t)i*MAT;
        float acc = 0.f;
        for (int o = 0; o < CC; ++o)
            acc += wf[o*CC + c] * wp[o*CC + t];
        A[(size_t)i*512*CC + (size_t)c*CC + t] = __float2bfloat16(acc);
    } else {
        idx -= 3*CC;
        int i = idx >> 8, o = idx & 255;
        const float* wo = Wo + (size_t)i*MAT;
        const float* wfu = Wfu + (size_t)o*(3*CC) + i*CC;
        float acc = 0.f;
        for (int c3 = 0; c3 < CC; ++c3)
            acc += wfu[c3] * wo[c3*CC + t];
        E[(size_t)i*MAT + (size_t)o*CC + t] = acc;
    }
}

__global__ __launch_bounds__(256) void k_mats2(
    const float* __restrict__ Wp, const float* __restrict__ E,
    __hip_bfloat16* __restrict__ A)
{
    int idx = blockIdx.x;
    int i = idx >> 8, o = idx & 255;
    int t = threadIdx.x;
    const float* e = E + (size_t)i*MAT + (size_t)o*CC;
    const float* wp = Wp + (size_t)i*MAT;
    float acc = 0.f;
    for (int c = 0; c < CC; ++c)
        acc += e[c] * wp[c*CC + t];
    A[(size_t)i*512*CC + (size_t)(256+o)*CC + t] = __float2bfloat16(acc);
}

// ---------------------------------------------------------------------------
// k_poolA_f32 (fallback path): fp32 x, one (b,c) per block. binsG[b][c][h][8].
// ---------------------------------------------------------------------------
__global__ __launch_bounds__(256, 4) void k_poolA_f32(
    const float* __restrict__ x, float* __restrict__ binsG)
{
    int bc = blockIdx.x;
    int t = threadIdx.x;
    const float4* xp = (const float4*)(x + (size_t)bc*HW) + t;
    __shared__ float bins[128][9];
    float4 v[16];
    #pragma unroll
    for (int i = 0; i < 16; ++i) v[i] = xp[i*256];
    int hb = t >> 5, bin = (t & 31) >> 2;
    #pragma unroll
    for (int i = 0; i < 16; ++i) {
        float s = v[i].x + v[i].y + v[i].z + v[i].w;
        s += __shfl_xor(s, 1);
        s += __shfl_xor(s, 2);
        if ((t & 3) == 0) bins[i*8 + hb][bin] = s;
    }
    __syncthreads();
    int h = t >> 1, b0 = (t & 1) * 4;
    float4 o;
    o.x = bins[h][b0+0]; o.y = bins[h][b0+1];
    o.z = bins[h][b0+2]; o.w = bins[h][b0+3];
    ((float4*)binsG)[(size_t)bc*256 + t] = o;
}

// ---------------------------------------------------------------------------
// k_poolA_bf (big path): reads xbf (L3-hot), same bins math in fp32.
// ---------------------------------------------------------------------------
__global__ __launch_bounds__(256, 4) void k_poolA_bf(
    const __hip_bfloat16* __restrict__ xb, float* __restrict__ binsG)
{
    int bc = blockIdx.x;
    int t = threadIdx.x;
    const ushort4* xp = (const ushort4*)(xb + (size_t)bc*HW) + t;
    __shared__ float bins[128][9];
    ushort4 v[16];
    #pragma unroll
    for (int i = 0; i < 16; ++i) v[i] = xp[i*256];
    int hb = t >> 5, bin = (t & 31) >> 2;
    #pragma unroll
    for (int i = 0; i < 16; ++i) {
        float s = __uint_as_float((uint32_t)v[i].x << 16)
                + __uint_as_float((uint32_t)v[i].y << 16)
                + __uint_as_float((uint32_t)v[i].z << 16)
                + __uint_as_float((uint32_t)v[i].w << 16);
        s += __shfl_xor(s, 1);
        s += __shfl_xor(s, 2);
        if ((t & 3) == 0) bins[i*8 + hb][bin] = s;
    }
    __syncthreads();
    int h = t >> 1, b0 = (t & 1) * 4;
    float4 o;
    o.x = bins[h][b0+0]; o.y = bins[h][b0+1];
    o.z = bins[h][b0+2]; o.w = bins[h][b0+3];
    ((float4*)binsG)[(size_t)bc*256 + t] = o;
}

// ---------------------------------------------------------------------------
// k_poolB: binsG -> Bt (bf16), unchanged.
// ---------------------------------------------------------------------------
__global__ __launch_bounds__(256) void k_poolB(
    const float* __restrict__ binsG, __hip_bfloat16* __restrict__ Bt)
{
    int bh = blockIdx.x;
    int b = bh >> 7, h = bh & 127;
    int c = threadIdx.x;
    const float* g = binsG + (((size_t)b*256 + c)*128 + h)*8;
    float4 lo = *(const float4*)(g);
    float4 hi = *(const float4*)(g + 4);
    float b8[8] = {lo.x, lo.y, lo.z, lo.w, hi.x, hi.y, hi.z, hi.w};

    __hip_bfloat16* B0 = Bt;
    __hip_bfloat16* B1 = Bt + (size_t)N0*CC;
    __hip_bfloat16* B2 = Bt + (size_t)(N0+N1)*CC;
    B0[((size_t)bh*2 + 0)*CC + c] = __float2bfloat16((b8[0]+b8[1]+b8[2]+b8[3]) * (1.f/64.f));
    B0[((size_t)bh*2 + 1)*CC + c] = __float2bfloat16((b8[4]+b8[5]+b8[6]+b8[7]) * (1.f/64.f));
    #pragma unroll
    for (int j = 0; j < 4; ++j)
        B1[((size_t)bh*4 + j)*CC + c] = __float2bfloat16((b8[2*j]+b8[2*j+1]) * (1.f/32.f));
    #pragma unroll
    for (int j = 0; j < 8; ++j)
        B2[((size_t)bh*8 + j)*CC + c] = __float2bfloat16(b8[j] * (1.f/16.f));
}

// ---------------------------------------------------------------------------
// k_gemm: unchanged (bf16 Cc[bh][512][16] output).
// ---------------------------------------------------------------------------
__global__ __launch_bounds__(128) void k_gemm(
    const __hip_bfloat16* __restrict__ A,
    const __hip_bfloat16* __restrict__ Bt,
    __hip_bfloat16* __restrict__ Cc)
{
    int blk = blockIdx.x;
    int br, lb, LP, poff;
    if (blk < 256)      { br = 0; lb = blk;       LP = 1; poff = 0; }
    else if (blk < 768) { br = 1; lb = blk - 256; LP = 2; poff = 2; }
    else                { br = 2; lb = blk - 768; LP = 3; poff = 6; }
    size_t aoff  = (size_t)br*512*CC;
    size_t btoff = (br == 0) ? 0 : (br == 1 ? (size_t)N0*CC : (size_t)(N0+N1)*CC);
    const __hip_bfloat16* Ab = A  + aoff;
    const __hip_bfloat16* Bb = Bt + btoff;

    int rb = lb & 3, cb = lb >> 2;
    int wv = threadIdx.x >> 6, lane = threadIdx.x & 63;
    int row0 = rb*128 + wv*64;
    int col0 = cb*64;
    int lr = lane & 15, lk = (lane >> 4) * 8;

    f32x4 acc[4][4] = {};
    for (int kk = 0; kk < CC; kk += 32) {
        bf16x8 af[4], bfr[4];
        #pragma unroll
        for (int m = 0; m < 4; ++m)
            af[m] = *reinterpret_cast<const bf16x8*>(Ab + (size_t)(row0 + m*16 + lr)*CC + kk + lk);
        #pragma unroll
        for (int n = 0; n < 4; ++n)
            bfr[n] = *reinterpret_cast<const bf16x8*>(Bb + (size_t)(col0 + n*16 + lr)*CC + kk + lk);
        #pragma unroll
        for (int m = 0; m < 4; ++m)
            #pragma unroll
            for (int n = 0; n < 4; ++n)
                acc[m][n] = __builtin_amdgcn_mfma_f32_16x16x32_bf16(af[m], bfr[n], acc[m][n], 0, 0, 0);
    }

    int cr = (lane >> 4) * 4, ccol = lane & 15;
    int pm = (1 << LP) - 1;
    #pragma unroll
    for (int m = 0; m < 4; ++m) {
        #pragma unroll
        for (int n = 0; n < 4; ++n) {
            int colg = col0 + n*16 + ccol;
            int bh = colg >> LP, p = colg & pm;
            __hip_bfloat16* dst = Cc + (size_t)bh*8192 + poff + p;
            #pragma unroll
            for (int j = 0; j < 4; ++j) {
                int r = row0 + m*16 + cr + j;
                dst[r*16] = __float2bfloat16(acc[m][n][j]);
            }
        }
    }
}

// ---------------------------------------------------------------------------
// softmax helper
// ---------------------------------------------------------------------------
template<int L>
__device__ __forceinline__ void softmax2(float2* a) {
    float mx = a[0].x, my = a[0].y;
    #pragma unroll
    for (int j = 1; j < L; ++j) { mx = fmaxf(mx, a[j].x); my = fmaxf(my, a[j].y); }
    float sx = 0.f, sy = 0.f;
    #pragma unroll
    for (int j = 0; j < L; ++j) {
        a[j].x = __expf(a[j].x - mx); sx += a[j].x;
        a[j].y = __expf(a[j].y - my); sy += a[j].y;
    }
    float rx = 1.f / sx, ry = 1.f / sy;
    #pragma unroll
    for (int j = 0; j < L; ++j) { a[j].x *= rx; a[j].y *= ry; }
}

// ---------------------------------------------------------------------------
// k_main_bf (big path): v9 free-running DMA structure on bf16 x.
// 16 tiles x 32 channels; each wave stages its 8-ch slice as 2x1KB DMAs
// (4 ch per DMA), ring of 4 (32 KB LDS), prefetch 3, per-wave counted vmcnt,
// no per-tile barriers. 48 KB LDS total -> 3 blocks/CU.
// ---------------------------------------------------------------------------
__global__ __launch_bounds__(256, 4) void k_main_bf(
    const __hip_bfloat16* __restrict__ xb, const __hip_bfloat16* __restrict__ Cc,
    float* __restrict__ out)
{
    int bh = blockIdx.x;
    int b = bh >> 7, h = bh & 127;
    int t = threadIdx.x;
    int lane = t & 63;
    int wv = __builtin_amdgcn_readfirstlane(t >> 6);
    const uint32_t* Cb = (const uint32_t*)(Cc + (size_t)bh*8192);
    const __hip_bfloat16* xg = xb + ((size_t)b*CC)*HW + h*128;  // + c*HW
    float2* o2 = (float2*)out + ((size_t)b*CC)*(HW/2) + h*64 + lane;

    __shared__ __hip_bfloat16 xbuf[4][32*128];         // 32768 B
    __shared__ float att_sx[2][64][15];                // 7680 B
    __shared__ float att_sy[2][64][15];                // 7680 B

    float2 att[14];
    #pragma unroll
    for (int p = 0; p < 14; ++p) att[p] = make_float2(0.f, 0.f);

    // stage tile tt: this wave's 8-channel slice as 2 DMAs of 4 channels.
    // lane l -> channel c0+(l>>4), pixels (l&15)*8..+7 (16 B).
    auto STAGE = [&](int tt) {
        int cb = (tt & 7) * 32;
        __hip_bfloat16* bufp = xbuf[tt & 3];
        #pragma unroll
        for (int e = 0; e < 2; ++e) {
            int c0 = cb + wv*8 + e*4;
            const __hip_bfloat16* gp = xg + (size_t)(c0 + (lane >> 4))*HW + (lane & 15)*8;
            __hip_bfloat16* lp = &bufp[(wv*8 + e*4)*128];
            __builtin_amdgcn_global_load_lds((glb_u32_t*)gp, (lds_u32_t*)lp, 16, 0, 0);
        }
    };

    STAGE(0);
    STAGE(1);
    STAGE(2);

    #pragma unroll 1
    for (int tt = 0; tt < 16; ++tt) {
        if (tt == 8) {
            // ---- cross-wave att reduce + softmax (one-time drain is fine) ----
            if (wv >= 2) {
                #pragma unroll
                for (int p = 0; p < 14; ++p) {
                    att_sx[wv-2][lane][p] = att[p].x;
                    att_sy[wv-2][lane][p] = att[p].y;
                }
            }
            __syncthreads();
            if (wv < 2) {
                #pragma unroll
                for (int p = 0; p < 14; ++p) {
                    att[p].x += att_sx[wv][lane][p];
                    att[p].y += att_sy[wv][lane][p];
                }
                if (wv == 1) {
                    #pragma unroll
                    for (int p = 0; p < 14; ++p) {
                        att_sx[1][lane][p] = att[p].x;
                        att_sy[1][lane][p] = att[p].y;
                    }
                }
            }
            __syncthreads();
            if (wv == 0) {
                #pragma unroll
                for (int p = 0; p < 14; ++p) {
                    att[p].x = (att[p].x + att_sx[1][lane][p]) * 0.0625f;
                    att[p].y = (att[p].y + att_sy[1][lane][p]) * 0.0625f;
                }
                softmax2<2>(att + 0);
                softmax2<4>(att + 2);
                softmax2<8>(att + 6);
                #pragma unroll
                for (int p = 0; p < 14; ++p) {
                    att_sx[0][lane][p] = att[p].x;
                    att_sy[0][lane][p] = att[p].y;
                }
            }
            __syncthreads();
            #pragma unroll
            for (int p = 0; p < 14; ++p) {
                att[p].x = att_sx[0][lane][p];
                att[p].y = att_sy[0][lane][p];
            }
        }

        // per-wave pacing: tile tt's 2 DMAs done. Queue math (issue order
        // [wait][STAGE tt+3][consume tt incl. stores in pass B]):
        //   tt<=8: newer-than-DMA(tt) = DMA(tt+1,tt+2) = 4
        //   tt=9: +stores(8) after DMA(9)? DMA(9)@iter6 -> newer = 12
        //   tt=10: 20; tt=11..13: 28; tt=14: 26; tt=15: 24.
        if (tt <= 8)       asm volatile("s_waitcnt vmcnt(4)"  ::: "memory");
        else if (tt == 9)  asm volatile("s_waitcnt vmcnt(12)" ::: "memory");
        else if (tt == 10) asm volatile("s_waitcnt vmcnt(20)" ::: "memory");
        else if (tt <= 13) asm volatile("s_waitcnt vmcnt(28)" ::: "memory");
        else if (tt == 14) asm volatile("s_waitcnt vmcnt(26)" ::: "memory");
        else               asm volatile("s_waitcnt vmcnt(24)" ::: "memory");
        __builtin_amdgcn_sched_barrier(0);

        if (tt + 3 < 16) STAGE(tt + 3);

        // ---- consume tile tt: this wave's 8 channels ----
        {
            int cb = (tt & 7) * 32;
            bool passB = (tt >= 8);
            const uint32_t* xrow = (const uint32_t*)&xbuf[tt & 3][(wv*8)*128];
            int crow = (passB ? 256 : 0) + cb + wv*8;
            const uint32_t* wr = Cb + (size_t)crow*8;
            #pragma unroll
            for (int half = 0; half < 2; ++half) {
                uint32_t u[4][7];
                #pragma unroll
                for (int q = 0; q < 4; ++q)
                    #pragma unroll
                    for (int j = 0; j < 7; ++j)
                        u[q][j] = wr[(half*4 + q)*8 + j];   // wave-uniform s_loads
                #pragma unroll
                for (int q = 0; q < 4; ++q) {
                    int qq = half*4 + q;
                    uint32_t xu = xrow[qq*64 + lane];       // 2 bf16 pixels
                    float2 xv;
                    xv.x = __uint_as_float(xu << 16);
                    xv.y = __uint_as_float(xu & 0xFFFF0000u);
                    if (!passB) {
                        #pragma unroll
                        for (int j = 0; j < 7; ++j) {
                            float mlo = __uint_as_float(u[q][j] << 16);
                            float mhi = __uint_as_float(u[q][j] & 0xFFFF0000u);
                            att[2*j].x   += xv.x * mlo;  att[2*j].y   += xv.y * mlo;
                            att[2*j+1].x += xv.x * mhi;  att[2*j+1].y += xv.y * mhi;
                        }
                    } else {
                        float2 acc = xv;                    // residual (bf16-rounded)
                        #pragma unroll
                        for (int j = 0; j < 7; ++j) {
                            float vlo = __uint_as_float(u[q][j] << 16);
                            float vhi = __uint_as_float(u[q][j] & 0xFFFF0000u);
                            acc.x += att[2*j].x * vlo;   acc.y += att[2*j].y * vlo;
                            acc.x += att[2*j+1].x * vhi; acc.y += att[2*j+1].y * vhi;
                        }
                        int o = cb + wv*8 + qq;
                        o2[(size_t)o*(HW/2)] = acc;
                    }
                }
            }
        }
    }
}

// ---------------------------------------------------------------------------
// k_main_f32 (fallback path): R9's v9, verbatim.
// ---------------------------------------------------------------------------
__global__ __launch_bounds__(256, 4) void k_main_f32(
    const float* __restrict__ x, const __hip_bfloat16* __restrict__ Cc,
    float* __restrict__ out)
{
    int bh = blockIdx.x;
    int b = bh >> 7, h = bh & 127;
    int t = threadIdx.x;
    int lane = t & 63;
    int wv = __builtin_amdgcn_readfirstlane(t >> 6);
    const uint32_t* Cb = (const uint32_t*)(Cc + (size_t)bh*8192);
    const float* xg = x  + ((size_t)b*CC)*HW + h*128;
    float*       og = out + ((size_t)b*CC)*HW + h*128;

    __shared__ float xbuf[4][32*128];
    __shared__ float att_sx[2][64][15];
    __shared__ float att_sy[2][64][15];

    float2 att[14];
    #pragma unroll
    for (int p = 0; p < 14; ++p) att[p] = make_float2(0.f, 0.f);

    auto STAGE = [&](int tt) {
        int cb = (tt & 7) * 32;
        float* bufp = xbuf[tt & 3];
        #pragma unroll
        for (int q = 0; q < 4; ++q) {
            int c0 = cb + wv*8 + q*2;
            const float* gp = xg + (size_t)(c0 + (lane >> 5))*HW + (lane & 31)*4;
            float* lp = &bufp[(wv*8 + q*2)*128];
            __builtin_amdgcn_global_load_lds((glb_u32_t*)gp, (lds_u32_t*)lp, 16, 0, 0);
        }
    };

    STAGE(0); STAGE(1); STAGE(2);

    #pragma unroll 1
    for (int tt = 0; tt < 16; ++tt) {
        if (tt == 8) {
            if (wv >= 2) {
                #pragma unroll
                for (int p = 0; p < 14; ++p) {
                    att_sx[wv-2][lane][p] = att[p].x;
                    att_sy[wv-2][lane][p] = att[p].y;
                }
            }
            __syncthreads();
            if (wv < 2) {
                #pragma unroll
                for (int p = 0; p < 14; ++p) {
                    att[p].x += att_sx[wv][lane][p];
                    att[p].y += att_sy[wv][lane][p];
                }
                if (wv == 1) {
                    #pragma unroll
                    for (int p = 0; p < 14; ++p) {
                        att_sx[1][lane][p] = att[p].x;
                        att_sy[1][lane][p] = att[p].y;
                    }
                }
            }
            __syncthreads();
            if (wv == 0) {
                #pragma unroll
                for (int p = 0; p < 14; ++p) {
                    att[p].x = (att[p].x + att_sx[1][lane][p]) * 0.0625f;
                    att[p].y = (att[p].y + att_sy[1][lane][p]) * 0.0625f;
                }
                softmax2<2>(att + 0);
                softmax2<4>(att + 2);
                softmax2<8>(att + 6);
                #pragma unroll
                for (int p = 0; p < 14; ++p) {
                    att_sx[0][lane][p] = att[p].x;
                    att_sy[0][lane][p] = att[p].y;
                }
            }
            __syncthreads();
            #pragma unroll
            for (int p = 0; p < 14; ++p) {
                att[p].x = att_sx[0][lane][p];
                att[p].y = att_sy[0][lane][p];
            }
        }

        if (tt < 8)       asm volatile("s_waitcnt vmcnt(8)"  ::: "memory");
        else if (tt < 14) asm volatile("s_waitcnt vmcnt(16)" ::: "memory");
        else if (tt == 14) asm volatile("s_waitcnt vmcnt(12)" ::: "memory");
        else               asm volatile("s_waitcnt vmcnt(8)"  ::: "memory");
        __builtin_amdgcn_sched_barrier(0);

        if (tt + 3 < 16) STAGE(tt + 3);

        {
            int cb = (tt & 7) * 32;
            bool passB = (tt >= 8);
            const float* xbuf_w = &xbuf[tt & 3][(wv*8)*128];
            int crow = (passB ? 256 : 0) + cb + wv*8;
            const uint32_t* wr = Cb + (size_t)crow*8;
            #pragma unroll
            for (int half = 0; half < 2; ++half) {
                uint32_t u[4][7];
                #pragma unroll
                for (int q = 0; q < 4; ++q)
                    #pragma unroll
                    for (int j = 0; j < 7; ++j)
                        u[q][j] = wr[(half*4 + q)*8 + j];
                #pragma unroll
                for (int q = 0; q < 4; ++q) {
                    int qq = half*4 + q;
                    float2 xv = *(const float2*)&xbuf_w[qq*128 + lane*2];
                    if (!passB) {
                        #pragma unroll
                        for (int j = 0; j < 7; ++j) {
                            float mlo = __uint_as_float(u[q][j] << 16);
                            float mhi = __uint_as_float(u[q][j] & 0xFFFF0000u);
                            att[2*j].x   += xv.x * mlo;  att[2*j].y   += xv.y * mlo;
                            att[2*j+1].x += xv.x * mhi;  att[2*j+1].y += xv.y * mhi;
                        }
                    } else {
                        float2 acc = xv;
                        #pragma unroll
                        for (int j = 0; j < 7; ++j) {
                            float vlo = __uint_as_float(u[q][j] << 16);
                            float vhi = __uint_as_float(u[q][j] & 0xFFFF0000u);
                            acc.x += att[2*j].x * vlo;   acc.y += att[2*j].y * vlo;
                            acc.x += att[2*j+1].x * vhi; acc.y += att[2*j+1].y * vhi;
                        }
                        int o = cb + wv*8 + qq;
                        *(float2*)&og[(size_t)o*HW + lane*2] = acc;
                    }
                }
            }
        }
    }
}

// ---------------------------------------------------------------------------
extern "C" void kernel_launch(void* const* d_in, const int* in_sizes, int n_in,
                              void* d_out, int out_size, void* d_ws, size_t ws_size,
                              hipStream_t stream)
{
    (void)in_sizes; (void)n_in; (void)out_size;
    const float* x   = (const float*)d_in[0];
    const float* Wp  = (const float*)d_in[1];
    const float* Wf  = (const float*)d_in[2];
    const float* Wo  = (const float*)d_in[3];
    const float* Wfu = (const float*)d_in[4];
    float* out = (float*)d_out;

    // workspace layout (bytes):
    //   E     fp32 3*MAT          @ 0         =    786432
    //   A     bf16 3*512*256      @ 786432    =    786432
    //   Bt    bf16 28672*256      @ 1572864   =  14680064
    //   Cc    bf16 2048*512*16    @ 16252928  =  33554432  (binsG fp32 aliases)
    //   xbf   bf16 16*256*16384   @ 49807360  = 134217728  (big path only)
    char* wsb = (char*)d_ws;
    float*          E     = (float*)wsb;
    __hip_bfloat16* A     = (__hip_bfloat16*)(wsb + 786432);
    __hip_bfloat16* Bt    = (__hip_bfloat16*)(wsb + 1572864);
    __hip_bfloat16* Cc    = (__hip_bfloat16*)(wsb + 16252928);
    float*          binsG = (float*)(wsb + 16252928);
    __hip_bfloat16* xbf   = (__hip_bfloat16*)(wsb + 49807360);

    const size_t NEED_BIG = 49807360u + 134217728u;    // 184 MB

    k_mats1<<<dim3(6*CC), dim3(256), 0, stream>>>(Wp, Wf, Wo, Wfu, A, E);
    k_mats2<<<dim3(3*CC), dim3(256), 0, stream>>>(Wp, E, A);

    if (ws_size >= NEED_BIG) {
        k_cast   <<<dim3(2048), dim3(256), 0, stream>>>((const float4*)x, (ushort4*)xbf);
        k_poolA_bf<<<dim3(4096), dim3(256), 0, stream>>>(xbf, binsG);
        k_poolB  <<<dim3(NBH),  dim3(256), 0, stream>>>(binsG, Bt);
        k_gemm   <<<dim3(1792), dim3(128), 0, stream>>>(A, Bt, Cc);
        k_main_bf<<<dim3(NBH),  dim3(256), 0, stream>>>(xbf, Cc, out);
    } else {
        k_poolA_f32<<<dim3(4096), dim3(256), 0, stream>>>(x, binsG);
        k_poolB  <<<dim3(NBH),  dim3(256), 0, stream>>>(binsG, Bt);
        k_gemm   <<<dim3(1792), dim3(128), 0, stream>>>(A, Bt, Cc);
        k_main_f32<<<dim3(NBH), dim3(256), 0, stream>>>(x, Cc, out);
    }
}